// Round 1
// baseline (2991.149 us; speedup 1.0000x reference)
//
#include <hip/hip_runtime.h>

#define S 4096
#define Dm 512
#define NH 8
#define DKh 64
#define NB 2

// ---------------- Kernel 1: fused QKV projection ----------------
// Q/K/V = X[8192,512] @ W*^T  (W rows are output features; y[m,j]=dot(x[m,:],W[j,:]))
__global__ __launch_bounds__(256, 3)
void qkv_gemm(const float* __restrict__ X,
              const float* __restrict__ Wq,
              const float* __restrict__ Wk,
              const float* __restrict__ Wv,
              float* __restrict__ Qo, float* __restrict__ Ko, float* __restrict__ Vo)
{
    __shared__ __align__(16) float As[32][132];
    __shared__ __align__(16) float Bs[32][132];
    const int tid = threadIdx.x;
    const int m0 = blockIdx.y * 128;
    const int n0 = blockIdx.x * 128;          // logical col in [0,1536)
    const int mat = n0 >> 9;                  // 0=Q,1=K,2=V (tiles never straddle 512)
    const float* W = (mat == 0) ? Wq : (mat == 1) ? Wk : Wv;
    float* Yo      = (mat == 0) ? Qo : (mat == 1) ? Ko : Vo;
    const int nb = n0 & 511;

    const int tm = tid & 15, tn = tid >> 4;
    float acc[8][8];
#pragma unroll
    for (int r = 0; r < 8; ++r)
#pragma unroll
        for (int c = 0; c < 8; ++c) acc[r][c] = 0.f;

    for (int k0 = 0; k0 < 512; k0 += 32) {
        __syncthreads();
#pragma unroll
        for (int i = 0; i < 4; ++i) {
            int f = i * 256 + tid;            // 1024 float4s per tile
            int row = f >> 3, c4 = f & 7;
            float4 a = *(const float4*)(X + (size_t)(m0 + row) * 512 + k0 + c4 * 4);
            As[c4*4+0][row] = a.x; As[c4*4+1][row] = a.y; As[c4*4+2][row] = a.z; As[c4*4+3][row] = a.w;
            float4 b = *(const float4*)(W + (size_t)(nb + row) * 512 + k0 + c4 * 4);
            Bs[c4*4+0][row] = b.x; Bs[c4*4+1][row] = b.y; Bs[c4*4+2][row] = b.z; Bs[c4*4+3][row] = b.w;
        }
        __syncthreads();
#pragma unroll
        for (int k = 0; k < 32; ++k) {
            float4 alo = *(const float4*)&As[k][tm * 4];
            float4 ahi = *(const float4*)&As[k][64 + tm * 4];
            float4 blo = *(const float4*)&Bs[k][tn * 4];
            float4 bhi = *(const float4*)&Bs[k][64 + tn * 4];
            float a[8] = {alo.x, alo.y, alo.z, alo.w, ahi.x, ahi.y, ahi.z, ahi.w};
            float b[8] = {blo.x, blo.y, blo.z, blo.w, bhi.x, bhi.y, bhi.z, bhi.w};
#pragma unroll
            for (int r = 0; r < 8; ++r)
#pragma unroll
                for (int c = 0; c < 8; ++c) acc[r][c] = fmaf(a[r], b[c], acc[r][c]);
        }
    }
#pragma unroll
    for (int r = 0; r < 8; ++r) {
        int m = m0 + ((r < 4) ? (tm * 4 + r) : (64 + tm * 4 + r - 4));
#pragma unroll
        for (int cc = 0; cc < 2; ++cc) {
            int c0 = (cc == 0) ? tn * 4 : 64 + tn * 4;
            float4 v = make_float4(acc[r][cc*4+0], acc[r][cc*4+1], acc[r][cc*4+2], acc[r][cc*4+3]);
            *(float4*)(Yo + (size_t)m * 512 + nb + c0) = v;
        }
    }
}

// ---------------- Kernel 2: fused attention ----------------
// Faithful numerics: s_fp32 -> s + (-1e9f) (fp32 rounding IS the reference's
// masked-softmax behavior) -> *0.125f -> softmax over the 8 HEADS (shfl over
// 8-lane groups). No coupling over k => k-range split across 2 buffers.
__global__ __launch_bounds__(256, 2)
void attn_fused(const float* __restrict__ Qg,
                const float* __restrict__ Kg,
                const float* __restrict__ Vg,
                float* __restrict__ P0, float* __restrict__ P1)
{
    __shared__ __align__(16) float Ks[16][8][68];  // [ki][h][d+pad4]
    __shared__ __align__(16) float Vs[16][8][68];
    const int tid = threadIdx.x;
    const int qi = tid >> 3;                  // 0..31
    const int h  = tid & 7;                   // head, 8-lane softmax group
    const int b  = blockIdx.y;
    const int q0 = blockIdx.x * 32;
    const int split = blockIdx.z;
    const int kbeg = split * (S / 2);
    const int qg = q0 + qi;

    const float* Qrow = Qg + (size_t)b * S * Dm + (size_t)qg * Dm + h * DKh;
    float4 qv[16];
#pragma unroll
    for (int i = 0; i < 16; ++i) qv[i] = *(const float4*)(Qrow + i * 4);

    float4 accv[16];
#pragma unroll
    for (int i = 0; i < 16; ++i) accv[i] = make_float4(0.f, 0.f, 0.f, 0.f);

    const float* Kbase = Kg + (size_t)b * S * Dm;
    const float* Vbase = Vg + (size_t)b * S * Dm;

    for (int kc = 0; kc < (S / 2) / 16; ++kc) {
        const int kbase = kbeg + kc * 16;
        __syncthreads();
        const float* Kb = Kbase + (size_t)kbase * Dm;
        const float* Vb = Vbase + (size_t)kbase * Dm;
#pragma unroll
        for (int i = 0; i < 8; ++i) {
            int f = i * 256 + tid;            // 2048 float4s per 16x512 tile
            int row = f >> 7;
            int c = (f & 127) * 4;
            *(float4*)&Ks[row][c >> 6][c & 63] = *(const float4*)(Kb + (size_t)row * Dm + c);
            *(float4*)&Vs[row][c >> 6][c & 63] = *(const float4*)(Vb + (size_t)row * Dm + c);
        }
        __syncthreads();
#pragma unroll 2
        for (int ki = 0; ki < 16; ++ki) {
            float s0 = 0.f, s1 = 0.f, s2 = 0.f, s3 = 0.f;
#pragma unroll
            for (int d4 = 0; d4 < 16; ++d4) {
                float4 kv = *(const float4*)&Ks[ki][h][d4 * 4];
                s0 = fmaf(qv[d4].x, kv.x, s0);
                s1 = fmaf(qv[d4].y, kv.y, s1);
                s2 = fmaf(qv[d4].z, kv.z, s2);
                s3 = fmaf(qv[d4].w, kv.w, s3);
            }
            float s = (s0 + s1) + (s2 + s3);
            const int kg = kbase + ki;
            s = s + ((kg > qg) ? -1e9f : 0.0f);   // EXACT reference rounding
            float x = s * 0.125f;                 // /sqrt(64), exact
            float m = x;
            m = fmaxf(m, __shfl_xor(m, 1));
            m = fmaxf(m, __shfl_xor(m, 2));
            m = fmaxf(m, __shfl_xor(m, 4));
            float e = __expf(x - m);
            float den = e;
            den += __shfl_xor(den, 1);
            den += __shfl_xor(den, 2);
            den += __shfl_xor(den, 4);
            float a = e / den;
#pragma unroll
            for (int d4 = 0; d4 < 16; ++d4) {
                float4 vv = *(const float4*)&Vs[ki][h][d4 * 4];
                accv[d4].x = fmaf(a, vv.x, accv[d4].x);
                accv[d4].y = fmaf(a, vv.y, accv[d4].y);
                accv[d4].z = fmaf(a, vv.z, accv[d4].z);
                accv[d4].w = fmaf(a, vv.w, accv[d4].w);
            }
        }
    }
    float* P = ((split == 0) ? P0 : P1) + (size_t)b * S * Dm + (size_t)qg * Dm + h * DKh;
#pragma unroll
    for (int i = 0; i < 16; ++i) *(float4*)(P + i * 4) = accv[i];
}

// ---------------- Kernel 3: out projection + ReLU ----------------
// out = relu((P0+P1) @ Wc^T), M=8192 N=512 K=512
__global__ __launch_bounds__(256, 4)
void out_gemm_relu(const float* __restrict__ P0,
                   const float* __restrict__ P1,
                   const float* __restrict__ Wc,
                   float* __restrict__ Out)
{
    __shared__ __align__(16) float As[32][68];
    __shared__ __align__(16) float Bs[32][132];
    const int tid = threadIdx.x;
    const int m0 = blockIdx.y * 64;
    const int n0 = blockIdx.x * 128;
    const int tm = tid & 15, tn = tid >> 4;
    float acc[4][8];
#pragma unroll
    for (int r = 0; r < 4; ++r)
#pragma unroll
        for (int c = 0; c < 8; ++c) acc[r][c] = 0.f;

    for (int k0 = 0; k0 < 512; k0 += 32) {
        __syncthreads();
#pragma unroll
        for (int i = 0; i < 2; ++i) {         // A: 64x32 = 512 f4
            int f = i * 256 + tid;
            int row = f >> 3, c4 = f & 7;
            size_t idx = (size_t)(m0 + row) * 512 + k0 + c4 * 4;
            float4 a = *(const float4*)(P0 + idx);
            float4 bb = *(const float4*)(P1 + idx);
            a.x += bb.x; a.y += bb.y; a.z += bb.z; a.w += bb.w;
            As[c4*4+0][row] = a.x; As[c4*4+1][row] = a.y; As[c4*4+2][row] = a.z; As[c4*4+3][row] = a.w;
        }
#pragma unroll
        for (int i = 0; i < 4; ++i) {         // B: 128x32 = 1024 f4
            int f = i * 256 + tid;
            int row = f >> 3, c4 = f & 7;
            float4 bw = *(const float4*)(Wc + (size_t)(n0 + row) * 512 + k0 + c4 * 4);
            Bs[c4*4+0][row] = bw.x; Bs[c4*4+1][row] = bw.y; Bs[c4*4+2][row] = bw.z; Bs[c4*4+3][row] = bw.w;
        }
        __syncthreads();
#pragma unroll
        for (int k = 0; k < 32; ++k) {
            float4 a4  = *(const float4*)&As[k][tm * 4];
            float4 blo = *(const float4*)&Bs[k][tn * 4];
            float4 bhi = *(const float4*)&Bs[k][64 + tn * 4];
            float a[4] = {a4.x, a4.y, a4.z, a4.w};
            float bv[8] = {blo.x, blo.y, blo.z, blo.w, bhi.x, bhi.y, bhi.z, bhi.w};
#pragma unroll
            for (int r = 0; r < 4; ++r)
#pragma unroll
                for (int c = 0; c < 8; ++c) acc[r][c] = fmaf(a[r], bv[c], acc[r][c]);
        }
    }
#pragma unroll
    for (int r = 0; r < 4; ++r) {
        int m = m0 + tm * 4 + r;
#pragma unroll
        for (int cc = 0; cc < 2; ++cc) {
            int c0 = (cc == 0) ? tn * 4 : 64 + tn * 4;
            float4 v = make_float4(fmaxf(acc[r][cc*4+0], 0.f), fmaxf(acc[r][cc*4+1], 0.f),
                                   fmaxf(acc[r][cc*4+2], 0.f), fmaxf(acc[r][cc*4+3], 0.f));
            *(float4*)(Out + (size_t)m * 512 + n0 + c0) = v;
        }
    }
}

extern "C" void kernel_launch(void* const* d_in, const int* in_sizes, int n_in,
                              void* d_out, int out_size, void* d_ws, size_t ws_size,
                              hipStream_t stream)
{
    const float* x  = (const float*)d_in[0];
    const float* Wq = (const float*)d_in[1];
    const float* Wk = (const float*)d_in[2];
    const float* Wv = (const float*)d_in[3];
    const float* Wc = (const float*)d_in[4];
    float* out = (float*)d_out;
    float* ws  = (float*)d_ws;

    const size_t NQ = (size_t)NB * S * Dm;    // 4,194,304 floats
    float* Qb = ws;
    float* Kb = ws + NQ;
    float* Vb = ws + 2 * NQ;
    float* P0 = ws + 3 * NQ;
    float* P1 = ws + 4 * NQ;                  // total 83.9 MB of d_ws

    qkv_gemm<<<dim3(12, 64), 256, 0, stream>>>(x, Wq, Wk, Wv, Qb, Kb, Vb);
    attn_fused<<<dim3(128, NB, 2), 256, 0, stream>>>(Qb, Kb, Vb, P0, P1);
    out_gemm_relu<<<dim3(4, 128), 256, 0, stream>>>(P0, P1, Wc, out);
}

// Round 2
// 1233.114 us; speedup vs baseline: 2.4257x; 2.4257x over previous
//
#include <hip/hip_runtime.h>

typedef __attribute__((ext_vector_type(8))) short short8;
typedef __attribute__((ext_vector_type(4))) float f32x4;

#define S 4096
#define Dm 512

__device__ __forceinline__ ushort f2bf(float f) {
    union { float f; unsigned u; } v; v.f = f;
    unsigned r = v.u + 0x7FFFu + ((v.u >> 16) & 1u);
    return (ushort)(r >> 16);
}
__device__ __forceinline__ float bf2f(ushort h) {
    union { unsigned u; float f; } v; v.u = ((unsigned)h) << 16; return v.f;
}

__device__ __forceinline__ void gload_lds16(const ushort* g, ushort* l) {
    __builtin_amdgcn_global_load_lds(
        (const __attribute__((address_space(1))) unsigned int*)g,
        (__attribute__((address_space(3))) unsigned int*)l, 16, 0, 0);
}

// ------------- kernel 1: cast fp32 -> bf16 hi/lo splits -------------
__global__ void cast_split(const float* __restrict__ x,
                           const float* __restrict__ Wq, const float* __restrict__ Wk,
                           const float* __restrict__ Wv, const float* __restrict__ Wc,
                           ushort* __restrict__ Xh, ushort* __restrict__ Xl,
                           ushort* __restrict__ Wqh, ushort* __restrict__ Wql,
                           ushort* __restrict__ Wkh, ushort* __restrict__ Wkl,
                           ushort* __restrict__ Wvh, ushort* __restrict__ Wch)
{
    const size_t i8 = ((size_t)blockIdx.x * 256 + threadIdx.x) * 8;
    const size_t NX = 4194304;
    float v[8];
    if (i8 < NX) {
        float4 a = *(const float4*)(x + i8);
        float4 b = *(const float4*)(x + i8 + 4);
        v[0]=a.x; v[1]=a.y; v[2]=a.z; v[3]=a.w; v[4]=b.x; v[5]=b.y; v[6]=b.z; v[7]=b.w;
        short8 h8, l8;
#pragma unroll
        for (int j = 0; j < 8; ++j) {
            ushort hi = f2bf(v[j]);
            h8[j] = (short)hi;
            l8[j] = (short)f2bf(v[j] - bf2f(hi));
        }
        *(short8*)(Xh + i8) = h8;
        *(short8*)(Xl + i8) = l8;
    } else {
        size_t j0 = i8 - NX;
        int wsel = (int)(j0 >> 18);
        size_t off = j0 & 262143;
        const float* src = (wsel == 0) ? Wq : (wsel == 1) ? Wk : (wsel == 2) ? Wv : Wc;
        float4 a = *(const float4*)(src + off);
        float4 b = *(const float4*)(src + off + 4);
        v[0]=a.x; v[1]=a.y; v[2]=a.z; v[3]=a.w; v[4]=b.x; v[5]=b.y; v[6]=b.z; v[7]=b.w;
        short8 h8, l8;
#pragma unroll
        for (int j = 0; j < 8; ++j) {
            ushort hi = f2bf(v[j]);
            h8[j] = (short)hi;
            l8[j] = (short)f2bf(v[j] - bf2f(hi));
        }
        ushort* dh = (wsel == 0) ? Wqh : (wsel == 1) ? Wkh : (wsel == 2) ? Wvh : Wch;
        *(short8*)(dh + off) = h8;
        if (wsel < 2) {
            ushort* dl = wsel ? Wkl : Wql;
            *(short8*)(dl + off) = l8;
        }
    }
}

// ------------- kernel 2: QKV projection (bf16 MFMA; Q,K in split precision) ----
__global__ __launch_bounds__(256, 2)
void qkv_gemm(const ushort* __restrict__ Xh, const ushort* __restrict__ Xl,
              const ushort* __restrict__ Wqh, const ushort* __restrict__ Wql,
              const ushort* __restrict__ Wkh, const ushort* __restrict__ Wkl,
              const ushort* __restrict__ Wvh,
              ushort* __restrict__ Qh, ushort* __restrict__ Ql,
              ushort* __restrict__ Kh, ushort* __restrict__ Kl,
              ushort* __restrict__ Vb)
{
    __shared__ ushort xh_sm[128 * 32];
    __shared__ ushort xl_sm[128 * 32];
    const int tid = threadIdx.x;
    const int w = tid >> 6, l = tid & 63, lq = l & 15, lg = l >> 4;
    const int wm = w >> 1, wn = w & 1;
    const int z = blockIdx.z;
    const int m0 = blockIdx.y * 128, n0 = blockIdx.x * 128;
    const ushort* Wh = (z == 0) ? Wqh : (z == 1) ? Wkh : Wvh;
    const ushort* Wl = (z == 0) ? Wql : Wkl;   // unused when z==2

    f32x4 acc[4][4];
#pragma unroll
    for (int i = 0; i < 4; ++i)
#pragma unroll
        for (int j = 0; j < 4; ++j) acc[i][j] = (f32x4){0.f, 0.f, 0.f, 0.f};

    for (int k0 = 0; k0 < 512; k0 += 32) {
        __syncthreads();
#pragma unroll
        for (int it = 0; it < 2; ++it) {
            int L = it * 256 + tid;
            int row = L >> 2, c = L & 3;
            int p = c ^ ((row >> 1) & 3);
            short8 vv = *(const short8*)(Xh + (size_t)(m0 + row) * Dm + k0 + c * 8);
            *(short8*)&xh_sm[row * 32 + p * 8] = vv;
            if (z < 2) {
                short8 v2 = *(const short8*)(Xl + (size_t)(m0 + row) * Dm + k0 + c * 8);
                *(short8*)&xl_sm[row * 32 + p * 8] = v2;
            }
        }
        __syncthreads();
        short8 bh[4], bl[4];
#pragma unroll
        for (int ns = 0; ns < 4; ++ns) {
            bh[ns] = *(const short8*)(Wh + (size_t)(n0 + wn * 64 + ns * 16 + lq) * Dm + k0 + lg * 8);
            if (z < 2)
                bl[ns] = *(const short8*)(Wl + (size_t)(n0 + wn * 64 + ns * 16 + lq) * Dm + k0 + lg * 8);
        }
#pragma unroll
        for (int ms = 0; ms < 4; ++ms) {
            int row = wm * 64 + ms * 16 + lq;
            int p = lg ^ ((row >> 1) & 3);
            short8 ah = *(const short8*)&xh_sm[row * 32 + p * 8];
            if (z < 2) {
                short8 al = *(const short8*)&xl_sm[row * 32 + p * 8];
#pragma unroll
                for (int ns = 0; ns < 4; ++ns) {
                    acc[ms][ns] = __builtin_amdgcn_mfma_f32_16x16x32_bf16(ah, bh[ns], acc[ms][ns], 0, 0, 0);
                    acc[ms][ns] = __builtin_amdgcn_mfma_f32_16x16x32_bf16(ah, bl[ns], acc[ms][ns], 0, 0, 0);
                    acc[ms][ns] = __builtin_amdgcn_mfma_f32_16x16x32_bf16(al, bh[ns], acc[ms][ns], 0, 0, 0);
                    acc[ms][ns] = __builtin_amdgcn_mfma_f32_16x16x32_bf16(al, bl[ns], acc[ms][ns], 0, 0, 0);
                }
            } else {
#pragma unroll
                for (int ns = 0; ns < 4; ++ns)
                    acc[ms][ns] = __builtin_amdgcn_mfma_f32_16x16x32_bf16(ah, bh[ns], acc[ms][ns], 0, 0, 0);
            }
        }
    }
    ushort* Yh = (z == 0) ? Qh : (z == 1) ? Kh : Vb;
    ushort* Yl = (z == 0) ? Ql : Kl;
#pragma unroll
    for (int ms = 0; ms < 4; ++ms)
#pragma unroll
        for (int ns = 0; ns < 4; ++ns)
#pragma unroll
            for (int j = 0; j < 4; ++j) {
                int m = m0 + wm * 64 + ms * 16 + lg * 4 + j;
                int n = n0 + wn * 64 + ns * 16 + lq;
                float v = acc[ms][ns][j];
                ushort hi = f2bf(v);
                Yh[(size_t)m * Dm + n] = hi;
                if (z < 2) Yl[(size_t)m * Dm + n] = f2bf(v - bf2f(hi));
            }
}

// ------------- kernel 3: V -> V^T  ([b][s][f] -> [b][f][s]) -------------
__global__ void vt_transpose(const ushort* __restrict__ Vb, ushort* __restrict__ VtG)
{
    __shared__ ushort t_sm[64 * 65];
    const int tid = threadIdx.x;
    const int bz = blockIdx.z;
    const int s0 = blockIdx.x * 64;
    const int f0 = blockIdx.y * 64;
#pragma unroll
    for (int it = 0; it < 2; ++it) {
        int r = it * 32 + (tid >> 3);
        int c8 = tid & 7;
        short8 v = *(const short8*)(Vb + (size_t)bz * S * Dm + (size_t)(s0 + r) * Dm + f0 + c8 * 8);
#pragma unroll
        for (int j = 0; j < 8; ++j) t_sm[(c8 * 8 + j) * 65 + r] = (ushort)v[j];
    }
    __syncthreads();
#pragma unroll
    for (int it = 0; it < 2; ++it) {
        int fr = it * 32 + (tid >> 3);
        int sc8 = tid & 7;
        short8 o;
#pragma unroll
        for (int j = 0; j < 8; ++j) o[j] = (short)t_sm[fr * 65 + sc8 * 8 + j];
        *(short8*)(VtG + (size_t)bz * Dm * S + (size_t)(f0 + fr) * S + s0 + sc8 * 8) = o;
    }
}

// ------------- kernel 4: fused attention (softmax over HEADS, lane-local) -----
__global__ __launch_bounds__(256, 2)
void attn_fused(const ushort* __restrict__ Qhh, const ushort* __restrict__ Qll,
                const ushort* __restrict__ Khh, const ushort* __restrict__ Kll,
                const ushort* __restrict__ VtG,
                ushort* __restrict__ P0, ushort* __restrict__ P1)
{
    __shared__ ushort vt_lds[512 * 32];        // 32 KB, chunk-swizzled
    __shared__ ushort a_lds[4 * 8 * 16 * 40];  // 40 KB, per-wave attn weights
    const int tid = threadIdx.x;
    const int w = tid >> 6, l = tid & 63, lq = l & 15, lg = l >> 4;
    const int blk = blockIdx.x;
    const int grp = blk & 3;              // XCD-friendly: (b,split) groups interleaved
    const int qt = blk >> 2;
    const int bb = grp >> 1;
    const int split = grp & 1;
    ushort* __restrict__ Pp = split ? P1 : P0;
    const int q_first = qt * 64;
    const int qsc = q_first + w * 16 + lq;     // score-phase q (B-operand column)
    const size_t sbase = (size_t)bb * S * Dm;
    const size_t qoff = sbase + (size_t)qsc * Dm;

    // persistent Q-hi fragments (B-operand: contiguous 8 d per lane)
    short8 qf[8][2];
#pragma unroll
    for (int h = 0; h < 8; ++h)
#pragma unroll
        for (int ds = 0; ds < 2; ++ds)
            qf[h][ds] = *(const short8*)(Qhh + qoff + h * 64 + ds * 32 + lg * 8);

    f32x4 outa[8][4];
#pragma unroll
    for (int h = 0; h < 8; ++h)
#pragma unroll
        for (int d = 0; d < 4; ++d) outa[h][d] = (f32x4){0.f, 0.f, 0.f, 0.f};

    for (int kt = 0; kt < 64; ++kt) {
        const int k0 = split * 2048 + kt * 32;
        __syncthreads();   // prior PV reads of vt_lds complete
        // async stage V^T tile (512 feat rows x 32 k), source-swizzled chunks
#pragma unroll
        for (int it = 0; it < 8; ++it) {
            int L = it * 256 + tid;
            int row = L >> 2, p = L & 3;
            int c = p ^ ((row >> 1) & 3);
            gload_lds16(VtG + (size_t)bb * Dm * S + (size_t)row * S + k0 + c * 8,
                        &vt_lds[L * 8]);
        }
        const bool precise = (k0 + 31) > q_first;   // tile touches masked region
#pragma unroll
        for (int msub = 0; msub < 2; ++msub) {
            f32x4 sc[8];
#pragma unroll
            for (int h = 0; h < 8; ++h) sc[h] = (f32x4){0.f, 0.f, 0.f, 0.f};
            const int krow = k0 + msub * 16 + lq;
            const size_t koff = sbase + (size_t)krow * Dm;
            if (precise) {
#pragma unroll
                for (int h = 0; h < 8; ++h) {
#pragma unroll
                    for (int ds = 0; ds < 2; ++ds) {
                        const size_t fo = koff + h * 64 + ds * 32 + lg * 8;
                        short8 khf = *(const short8*)(Khh + fo);
                        short8 klf = *(const short8*)(Kll + fo);
                        short8 qlf = *(const short8*)(Qll + qoff + h * 64 + ds * 32 + lg * 8);
                        sc[h] = __builtin_amdgcn_mfma_f32_16x16x32_bf16(khf, qf[h][ds], sc[h], 0, 0, 0);
                        sc[h] = __builtin_amdgcn_mfma_f32_16x16x32_bf16(khf, qlf, sc[h], 0, 0, 0);
                        sc[h] = __builtin_amdgcn_mfma_f32_16x16x32_bf16(klf, qf[h][ds], sc[h], 0, 0, 0);
                        sc[h] = __builtin_amdgcn_mfma_f32_16x16x32_bf16(klf, qlf, sc[h], 0, 0, 0);
                    }
                }
            } else {
#pragma unroll
                for (int h = 0; h < 8; ++h)
#pragma unroll
                    for (int ds = 0; ds < 2; ++ds) {
                        short8 khf = *(const short8*)(Khh + koff + h * 64 + ds * 32 + lg * 8);
                        sc[h] = __builtin_amdgcn_mfma_f32_16x16x32_bf16(khf, qf[h][ds], sc[h], 0, 0, 0);
                    }
            }
            // softmax over the 8 heads -- entirely lane-local
            const int kbl = k0 + msub * 16 + lg * 4;
#pragma unroll
            for (int j = 0; j < 4; ++j) {
                float xx[8];
                const float madd = ((kbl + j) > qsc) ? -1e9f : 0.0f;
#pragma unroll
                for (int h = 0; h < 8; ++h)
                    xx[h] = (sc[h][j] + madd) * 0.125f;   // faithful fp32 rounding of s + (-1e9)
                float m01 = fmaxf(xx[0], xx[1]), m23 = fmaxf(xx[2], xx[3]);
                float m45 = fmaxf(xx[4], xx[5]), m67 = fmaxf(xx[6], xx[7]);
                float mm = fmaxf(fmaxf(m01, m23), fmaxf(m45, m67));
                float e[8]; float den = 0.f;
#pragma unroll
                for (int h = 0; h < 8; ++h) { e[h] = __expf(xx[h] - mm); den += e[h]; }
                float inv = 1.0f / den;
#pragma unroll
                for (int h = 0; h < 8; ++h) sc[h][j] = e[h] * inv;
            }
            // pack to bf16 and write per-wave A tile [q=lane&15][k]
#pragma unroll
            for (int h = 0; h < 8; ++h) {
                unsigned p01 = (unsigned)f2bf(sc[h][0]) | ((unsigned)f2bf(sc[h][1]) << 16);
                unsigned p23 = (unsigned)f2bf(sc[h][2]) | ((unsigned)f2bf(sc[h][3]) << 16);
                unsigned* dst = (unsigned*)&a_lds[(((w * 8 + h) * 16 + lq) * 40) + msub * 16 + lg * 4];
                dst[0] = p01; dst[1] = p23;
            }
        }
        __syncthreads();   // V^T staged (vmcnt drained at barrier); A writes visible
        // PV: out[q][d] += A[q,k] * V[k,d]
#pragma unroll
        for (int h = 0; h < 8; ++h) {
            short8 af = *(const short8*)&a_lds[(((w * 8 + h) * 16 + lq) * 40) + lg * 8];
#pragma unroll
            for (int dsub = 0; dsub < 4; ++dsub) {
                int row = h * 64 + dsub * 16 + lq;
                int p = lg ^ ((row >> 1) & 3);
                short8 vf = *(const short8*)&vt_lds[row * 32 + p * 8];
                outa[h][dsub] = __builtin_amdgcn_mfma_f32_16x16x32_bf16(af, vf, outa[h][dsub], 0, 0, 0);
            }
        }
    }
    // epilogue: partial P (this k-split) as bf16
#pragma unroll
    for (int h = 0; h < 8; ++h)
#pragma unroll
        for (int dsub = 0; dsub < 4; ++dsub)
#pragma unroll
            for (int j = 0; j < 4; ++j) {
                int qrow = q_first + w * 16 + lg * 4 + j;
                Pp[sbase + (size_t)qrow * Dm + h * 64 + dsub * 16 + lq] = f2bf(outa[h][dsub][j]);
            }
}

// ------------- kernel 5: sum the two k-split partials -------------
__global__ void p_reduce(const ushort* __restrict__ P0, const ushort* __restrict__ P1,
                         ushort* __restrict__ Pbf)
{
    size_t i8 = ((size_t)blockIdx.x * 256 + threadIdx.x) * 8;
    short8 a = *(const short8*)(P0 + i8);
    short8 b = *(const short8*)(P1 + i8);
    short8 o;
#pragma unroll
    for (int j = 0; j < 8; ++j)
        o[j] = (short)f2bf(bf2f((ushort)a[j]) + bf2f((ushort)b[j]));
    *(short8*)(Pbf + i8) = o;
}

// ------------- kernel 6: out projection + ReLU (fp32 out) -------------
__global__ __launch_bounds__(256, 2)
void out_gemm(const ushort* __restrict__ Pbf, const ushort* __restrict__ Wch,
              float* __restrict__ Out)
{
    __shared__ ushort a_sm[128 * 32];
    const int tid = threadIdx.x;
    const int w = tid >> 6, l = tid & 63, lq = l & 15, lg = l >> 4;
    const int wm = w >> 1, wn = w & 1;
    const int m0 = blockIdx.y * 128, n0 = blockIdx.x * 128;
    f32x4 acc[4][4];
#pragma unroll
    for (int i = 0; i < 4; ++i)
#pragma unroll
        for (int j = 0; j < 4; ++j) acc[i][j] = (f32x4){0.f, 0.f, 0.f, 0.f};

    for (int k0 = 0; k0 < 512; k0 += 32) {
        __syncthreads();
#pragma unroll
        for (int it = 0; it < 2; ++it) {
            int L = it * 256 + tid;
            int row = L >> 2, c = L & 3;
            int p = c ^ ((row >> 1) & 3);
            short8 vv = *(const short8*)(Pbf + (size_t)(m0 + row) * Dm + k0 + c * 8);
            *(short8*)&a_sm[row * 32 + p * 8] = vv;
        }
        __syncthreads();
        short8 bfrag[4];
#pragma unroll
        for (int ns = 0; ns < 4; ++ns)
            bfrag[ns] = *(const short8*)(Wch + (size_t)(n0 + wn * 64 + ns * 16 + lq) * Dm + k0 + lg * 8);
#pragma unroll
        for (int ms = 0; ms < 4; ++ms) {
            int row = wm * 64 + ms * 16 + lq;
            int p = lg ^ ((row >> 1) & 3);
            short8 afrag = *(const short8*)&a_sm[row * 32 + p * 8];
#pragma unroll
            for (int ns = 0; ns < 4; ++ns)
                acc[ms][ns] = __builtin_amdgcn_mfma_f32_16x16x32_bf16(afrag, bfrag[ns], acc[ms][ns], 0, 0, 0);
        }
    }
#pragma unroll
    for (int ms = 0; ms < 4; ++ms)
#pragma unroll
        for (int ns = 0; ns < 4; ++ns)
#pragma unroll
            for (int j = 0; j < 4; ++j) {
                int m = m0 + wm * 64 + ms * 16 + lg * 4 + j;
                int n = n0 + wn * 64 + ns * 16 + lq;
                Out[(size_t)m * Dm + n] = fmaxf(acc[ms][ns][j], 0.0f);
            }
}

extern "C" void kernel_launch(void* const* d_in, const int* in_sizes, int n_in,
                              void* d_out, int out_size, void* d_ws, size_t ws_size,
                              hipStream_t stream)
{
    const float* x  = (const float*)d_in[0];
    const float* Wq = (const float*)d_in[1];
    const float* Wk = (const float*)d_in[2];
    const float* Wv = (const float*)d_in[3];
    const float* Wc = (const float*)d_in[4];
    float* out = (float*)d_out;

    const size_t SZ = 4194304;   // 2*4096*512
    const size_t WZ = 262144;    // 512*512
    ushort* ws16 = (ushort*)d_ws;
    ushort* Xh  = ws16;           // reused as P0 after qkv
    ushort* Xl  = Xh + SZ;        // reused as P1 after qkv
    ushort* Wqh = Xl + SZ;
    ushort* Wql = Wqh + WZ;
    ushort* Wkh = Wql + WZ;
    ushort* Wkl = Wkh + WZ;
    ushort* Wvh = Wkl + WZ;
    ushort* Wch = Wvh + WZ;
    ushort* Qh  = Wch + WZ;
    ushort* Ql  = Qh + SZ;
    ushort* Kh  = Ql + SZ;
    ushort* Kl  = Kh + SZ;
    ushort* Vb  = Kl + SZ;
    ushort* Vt  = Vb + SZ;
    ushort* Pb  = Vt + SZ;        // total ~78.6 MB

    cast_split<<<2560, 256, 0, stream>>>(x, Wq, Wk, Wv, Wc, Xh, Xl,
                                         Wqh, Wql, Wkh, Wkl, Wvh, Wch);
    qkv_gemm<<<dim3(4, 64, 3), 256, 0, stream>>>(Xh, Xl, Wqh, Wql, Wkh, Wkl, Wvh,
                                                 Qh, Ql, Kh, Kl, Vb);
    vt_transpose<<<dim3(64, 8, 2), 256, 0, stream>>>(Vb, Vt);
    attn_fused<<<256, 256, 0, stream>>>(Qh, Ql, Kh, Kl, Vt, Xh, Xl);
    p_reduce<<<2048, 256, 0, stream>>>(Xh, Xl, Pb);
    out_gemm<<<dim3(4, 64), 256, 0, stream>>>(Pb, Wch, out);
}

// Round 3
// 1166.120 us; speedup vs baseline: 2.5650x; 1.0575x over previous
//
#include <hip/hip_runtime.h>

typedef __attribute__((ext_vector_type(8))) short short8;
typedef __attribute__((ext_vector_type(4))) float f32x4;

#define S 4096
#define Dm 512

__device__ __forceinline__ ushort f2bf(float f) {
    union { float f; unsigned u; } v; v.f = f;
    unsigned r = v.u + 0x7FFFu + ((v.u >> 16) & 1u);
    return (ushort)(r >> 16);
}
__device__ __forceinline__ float bf2f(ushort h) {
    union { unsigned u; float f; } v; v.u = ((unsigned)h) << 16; return v.f;
}

__device__ __forceinline__ void gload_lds16(const ushort* g, ushort* l) {
    __builtin_amdgcn_global_load_lds(
        (const __attribute__((address_space(1))) unsigned int*)g,
        (__attribute__((address_space(3))) unsigned int*)l, 16, 0, 0);
}

// ------------- kernel 1: cast fp32 -> bf16 hi/lo splits -------------
__global__ void cast_split(const float* __restrict__ x,
                           const float* __restrict__ Wq, const float* __restrict__ Wk,
                           const float* __restrict__ Wv, const float* __restrict__ Wc,
                           ushort* __restrict__ Xh, ushort* __restrict__ Xl,
                           ushort* __restrict__ Wqh, ushort* __restrict__ Wql,
                           ushort* __restrict__ Wkh, ushort* __restrict__ Wkl,
                           ushort* __restrict__ Wvh, ushort* __restrict__ Wch)
{
    const size_t i8 = ((size_t)blockIdx.x * 256 + threadIdx.x) * 8;
    const size_t NX = 4194304;
    float v[8];
    if (i8 < NX) {
        float4 a = *(const float4*)(x + i8);
        float4 b = *(const float4*)(x + i8 + 4);
        v[0]=a.x; v[1]=a.y; v[2]=a.z; v[3]=a.w; v[4]=b.x; v[5]=b.y; v[6]=b.z; v[7]=b.w;
        short8 h8, l8;
#pragma unroll
        for (int j = 0; j < 8; ++j) {
            ushort hi = f2bf(v[j]);
            h8[j] = (short)hi;
            l8[j] = (short)f2bf(v[j] - bf2f(hi));
        }
        *(short8*)(Xh + i8) = h8;
        *(short8*)(Xl + i8) = l8;
    } else {
        size_t j0 = i8 - NX;
        int wsel = (int)(j0 >> 18);
        size_t off = j0 & 262143;
        const float* src = (wsel == 0) ? Wq : (wsel == 1) ? Wk : (wsel == 2) ? Wv : Wc;
        float4 a = *(const float4*)(src + off);
        float4 b = *(const float4*)(src + off + 4);
        v[0]=a.x; v[1]=a.y; v[2]=a.z; v[3]=a.w; v[4]=b.x; v[5]=b.y; v[6]=b.z; v[7]=b.w;
        short8 h8, l8;
#pragma unroll
        for (int j = 0; j < 8; ++j) {
            ushort hi = f2bf(v[j]);
            h8[j] = (short)hi;
            l8[j] = (short)f2bf(v[j] - bf2f(hi));
        }
        ushort* dh = (wsel == 0) ? Wqh : (wsel == 1) ? Wkh : (wsel == 2) ? Wvh : Wch;
        *(short8*)(dh + off) = h8;
        if (wsel < 2) {
            ushort* dl = wsel ? Wkl : Wql;
            *(short8*)(dl + off) = l8;
        }
    }
}

// ------------- kernel 2: QKV projection (bf16 MFMA; Q,K in split precision) ----
__global__ __launch_bounds__(256, 2)
void qkv_gemm(const ushort* __restrict__ Xh, const ushort* __restrict__ Xl,
              const ushort* __restrict__ Wqh, const ushort* __restrict__ Wql,
              const ushort* __restrict__ Wkh, const ushort* __restrict__ Wkl,
              const ushort* __restrict__ Wvh,
              ushort* __restrict__ Qh, ushort* __restrict__ Ql,
              ushort* __restrict__ Kh, ushort* __restrict__ Kl,
              ushort* __restrict__ Vb)
{
    __shared__ ushort xh_sm[128 * 32];
    __shared__ ushort xl_sm[128 * 32];
    const int tid = threadIdx.x;
    const int w = tid >> 6, l = tid & 63, lq = l & 15, lg = l >> 4;
    const int wm = w >> 1, wn = w & 1;
    const int z = blockIdx.z;
    const int m0 = blockIdx.y * 128, n0 = blockIdx.x * 128;
    const ushort* Wh = (z == 0) ? Wqh : (z == 1) ? Wkh : Wvh;
    const ushort* Wl = (z == 0) ? Wql : Wkl;   // unused when z==2

    f32x4 acc[4][4];
#pragma unroll
    for (int i = 0; i < 4; ++i)
#pragma unroll
        for (int j = 0; j < 4; ++j) acc[i][j] = (f32x4){0.f, 0.f, 0.f, 0.f};

    for (int k0 = 0; k0 < 512; k0 += 32) {
        __syncthreads();
#pragma unroll
        for (int it = 0; it < 2; ++it) {
            int L = it * 256 + tid;
            int row = L >> 2, c = L & 3;
            int p = c ^ ((row >> 1) & 3);
            short8 vv = *(const short8*)(Xh + (size_t)(m0 + row) * Dm + k0 + c * 8);
            *(short8*)&xh_sm[row * 32 + p * 8] = vv;
            if (z < 2) {
                short8 v2 = *(const short8*)(Xl + (size_t)(m0 + row) * Dm + k0 + c * 8);
                *(short8*)&xl_sm[row * 32 + p * 8] = v2;
            }
        }
        __syncthreads();
        short8 bh[4], bl[4];
#pragma unroll
        for (int ns = 0; ns < 4; ++ns) {
            bh[ns] = *(const short8*)(Wh + (size_t)(n0 + wn * 64 + ns * 16 + lq) * Dm + k0 + lg * 8);
            if (z < 2)
                bl[ns] = *(const short8*)(Wl + (size_t)(n0 + wn * 64 + ns * 16 + lq) * Dm + k0 + lg * 8);
        }
#pragma unroll
        for (int ms = 0; ms < 4; ++ms) {
            int row = wm * 64 + ms * 16 + lq;
            int p = lg ^ ((row >> 1) & 3);
            short8 ah = *(const short8*)&xh_sm[row * 32 + p * 8];
            if (z < 2) {
                short8 al = *(const short8*)&xl_sm[row * 32 + p * 8];
#pragma unroll
                for (int ns = 0; ns < 4; ++ns) {
                    acc[ms][ns] = __builtin_amdgcn_mfma_f32_16x16x32_bf16(ah, bh[ns], acc[ms][ns], 0, 0, 0);
                    acc[ms][ns] = __builtin_amdgcn_mfma_f32_16x16x32_bf16(ah, bl[ns], acc[ms][ns], 0, 0, 0);
                    acc[ms][ns] = __builtin_amdgcn_mfma_f32_16x16x32_bf16(al, bh[ns], acc[ms][ns], 0, 0, 0);
                    acc[ms][ns] = __builtin_amdgcn_mfma_f32_16x16x32_bf16(al, bl[ns], acc[ms][ns], 0, 0, 0);
                }
            } else {
#pragma unroll
                for (int ns = 0; ns < 4; ++ns)
                    acc[ms][ns] = __builtin_amdgcn_mfma_f32_16x16x32_bf16(ah, bh[ns], acc[ms][ns], 0, 0, 0);
            }
        }
    }
    ushort* Yh = (z == 0) ? Qh : (z == 1) ? Kh : Vb;
    ushort* Yl = (z == 0) ? Ql : Kl;
#pragma unroll
    for (int ms = 0; ms < 4; ++ms)
#pragma unroll
        for (int ns = 0; ns < 4; ++ns)
#pragma unroll
            for (int j = 0; j < 4; ++j) {
                int m = m0 + wm * 64 + ms * 16 + lg * 4 + j;
                int n = n0 + wn * 64 + ns * 16 + lq;
                float v = acc[ms][ns][j];
                ushort hi = f2bf(v);
                Yh[(size_t)m * Dm + n] = hi;
                if (z < 2) Yl[(size_t)m * Dm + n] = f2bf(v - bf2f(hi));
            }
}

// ------------- kernel 3: V -> V^T k-tiled  ([b][s][f] -> [b][s/16][f][16]) -----
__global__ void vt_transpose(const ushort* __restrict__ Vb, ushort* __restrict__ VtG)
{
    __shared__ ushort t_sm[64 * 65];
    const int tid = threadIdx.x;
    const int bz = blockIdx.z;
    const int s0 = blockIdx.x * 64;
    const int f0 = blockIdx.y * 64;
#pragma unroll
    for (int it = 0; it < 2; ++it) {
        int r = it * 32 + (tid >> 3);
        int c8 = tid & 7;
        short8 v = *(const short8*)(Vb + (size_t)bz * S * Dm + (size_t)(s0 + r) * Dm + f0 + c8 * 8);
#pragma unroll
        for (int j = 0; j < 8; ++j) t_sm[(c8 * 8 + j) * 65 + r] = (ushort)v[j];
    }
    __syncthreads();
#pragma unroll
    for (int it = 0; it < 2; ++it) {
        int fr = it * 32 + (tid >> 3);
        int sc8 = tid & 7;
        short8 o;
#pragma unroll
        for (int j = 0; j < 8; ++j) o[j] = (short)t_sm[fr * 65 + sc8 * 8 + j];
        int ktile = (s0 >> 4) + (sc8 >> 1);
        int koff = (sc8 & 1) * 8;
        *(short8*)(VtG + (((size_t)bz * 256 + ktile) * 512 + (f0 + fr)) * 16 + koff) = o;
    }
}

// ------------- kernel 4: fused attention (softmax over HEADS, lane-local) -----
// block: 64 q (4 waves x 16 q), k-range 1024 (one of 4 splits), KT=16
__global__ __launch_bounds__(256, 2)
void attn_fused(const ushort* __restrict__ Qhh, const ushort* __restrict__ Qll,
                const ushort* __restrict__ Khh, const ushort* __restrict__ Kll,
                const ushort* __restrict__ VtG,
                ushort* __restrict__ P0, ushort* __restrict__ P1,
                ushort* __restrict__ P2, ushort* __restrict__ P3)
{
    __shared__ ushort Khi_lds[8192];    // [16 k][64 chunks of 8 d], src-swizzled (16KB)
    __shared__ ushort Vt_lds[16384];    // [2 slots][512 d][16 k]                (32KB)
    __shared__ ushort a_lds[16384];     // [4 w][8 h][16 q][32 k]                (32KB)
    const int tid = threadIdx.x;
    const int w = tid >> 6, l = tid & 63, lq = l & 15, lg = l >> 4;
    const int qt = blockIdx.x, bb = blockIdx.y, ks = blockIdx.z;
    const int q_first = qt * 64;
    const int ksbeg = ks * 1024;
    const int qsc = q_first + w * 16 + lq;
    const size_t sbase = (size_t)bb * S * Dm;
    const size_t qoff = sbase + (size_t)qsc * Dm;
    ushort* __restrict__ Pp = (ks == 0) ? P0 : (ks == 1) ? P1 : (ks == 2) ? P2 : P3;

    // persistent Q-hi fragments (B-operand: 8 contiguous d per lane)
    short8 qf[8][2];
#pragma unroll
    for (int h = 0; h < 8; ++h)
#pragma unroll
        for (int ds = 0; ds < 2; ++ds)
            qf[h][ds] = *(const short8*)(Qhh + qoff + h * 64 + ds * 32 + lg * 8);

    f32x4 outa[8][4];
#pragma unroll
    for (int h = 0; h < 8; ++h)
#pragma unroll
        for (int d = 0; d < 4; ++d) outa[h][d] = (f32x4){0.f, 0.f, 0.f, 0.f};

    for (int kc = 0; kc < 64; ++kc) {
        const int k0 = ksbeg + kc * 16;
        __syncthreads();    // all waves done reading buffers being overwritten
        // stage K-hi tile [16][512], source-swizzled so frag reads spread banks
#pragma unroll
        for (int it = 0; it < 4; ++it) {
            int L = it * 256 + tid;
            int row = L >> 6;
            int ch = (L & 63) ^ (row & 7);
            gload_lds16(Khh + sbase + (size_t)(k0 + row) * Dm + ch * 8, &Khi_lds[L * 8]);
        }
        // stage V^T k-slice (linear: VtG is k-tiled [b][k/16][512][16])
        {
            const size_t vsrc = ((size_t)bb * 256 + (k0 >> 4)) * (512 * 16);
            ushort* vdst = &Vt_lds[(kc & 1) * 8192];
#pragma unroll
            for (int it = 0; it < 4; ++it) {
                int L = it * 256 + tid;
                gload_lds16(VtG + vsrc + L * 8, vdst + L * 8);
            }
        }
        __syncthreads();    // stage complete (vmcnt drained at barrier)

        const bool precise = (k0 + 15) > q_first;   // tile touches masked region
        f32x4 sc[8];
#pragma unroll
        for (int h = 0; h < 8; ++h) sc[h] = (f32x4){0.f, 0.f, 0.f, 0.f};
#pragma unroll
        for (int h = 0; h < 8; ++h) {
#pragma unroll
            for (int ds = 0; ds < 2; ++ds) {
                int unit = lq * 64 + ((h * 8 + ds * 4 + lg) ^ (lq & 7));
                short8 khf = *(const short8*)&Khi_lds[unit * 8];
                sc[h] = __builtin_amdgcn_mfma_f32_16x16x32_bf16(khf, qf[h][ds], sc[h], 0, 0, 0);
                if (precise) {
                    short8 qlf = *(const short8*)(Qll + qoff + h * 64 + ds * 32 + lg * 8);
                    short8 klf = *(const short8*)(Kll + sbase + (size_t)(k0 + lq) * Dm + h * 64 + ds * 32 + lg * 8);
                    sc[h] = __builtin_amdgcn_mfma_f32_16x16x32_bf16(khf, qlf, sc[h], 0, 0, 0);
                    sc[h] = __builtin_amdgcn_mfma_f32_16x16x32_bf16(klf, qf[h][ds], sc[h], 0, 0, 0);
                }
            }
        }
        // softmax over the 8 heads -- lane-local
        const int kb = k0 + lg * 4;
#pragma unroll
        for (int j = 0; j < 4; ++j) {
            float xx[8];
            const float madd = ((kb + j) > qsc) ? -1e9f : 0.0f;
#pragma unroll
            for (int h = 0; h < 8; ++h)
                xx[h] = (sc[h][j] + madd) * 0.125f;   // faithful fp32 rounding of s + (-1e9)
            float m01 = fmaxf(xx[0], xx[1]), m23 = fmaxf(xx[2], xx[3]);
            float m45 = fmaxf(xx[4], xx[5]), m67 = fmaxf(xx[6], xx[7]);
            float mm = fmaxf(fmaxf(m01, m23), fmaxf(m45, m67));
            float e[8]; float den = 0.f;
#pragma unroll
            for (int h = 0; h < 8; ++h) { e[h] = __expf(xx[h] - mm); den += e[h]; }
            float inv = 1.0f / den;
#pragma unroll
            for (int h = 0; h < 8; ++h) sc[h][j] = e[h] * inv;
        }
        // pack bf16 into wave-private A tile (no barrier needed)
#pragma unroll
        for (int h = 0; h < 8; ++h) {
            unsigned p01 = (unsigned)f2bf(sc[h][0]) | ((unsigned)f2bf(sc[h][1]) << 16);
            unsigned p23 = (unsigned)f2bf(sc[h][2]) | ((unsigned)f2bf(sc[h][3]) << 16);
            unsigned* dst = (unsigned*)&a_lds[((w * 8 + h) * 16 + lq) * 32 + (kc & 1) * 16 + lg * 4];
            dst[0] = p01; dst[1] = p23;
        }
        if (kc & 1) {
            // PV over the 32-k window (both Vt slots + both a halves)
#pragma unroll
            for (int h = 0; h < 8; ++h) {
                short8 af = *(const short8*)&a_lds[((w * 8 + h) * 16 + lq) * 32 + lg * 8];
#pragma unroll
                for (int dsub = 0; dsub < 4; ++dsub) {
                    short8 vf = *(const short8*)&Vt_lds[(lg >> 1) * 8192 + (h * 64 + dsub * 16 + lq) * 16 + (lg & 1) * 8];
                    outa[h][dsub] = __builtin_amdgcn_mfma_f32_16x16x32_bf16(af, vf, outa[h][dsub], 0, 0, 0);
                }
            }
        }
    }
    // epilogue: partial P (this k-split) as bf16
#pragma unroll
    for (int h = 0; h < 8; ++h)
#pragma unroll
        for (int dsub = 0; dsub < 4; ++dsub)
#pragma unroll
            for (int j = 0; j < 4; ++j) {
                int qrow = q_first + w * 16 + lg * 4 + j;
                Pp[sbase + (size_t)qrow * Dm + h * 64 + dsub * 16 + lq] = f2bf(outa[h][dsub][j]);
            }
}

// ------------- kernel 5: out projection + ReLU (sums 4 partials, fp32 out) ----
__global__ __launch_bounds__(256, 2)
void out_gemm(const ushort* __restrict__ P0, const ushort* __restrict__ P1,
              const ushort* __restrict__ P2, const ushort* __restrict__ P3,
              const ushort* __restrict__ Wch, float* __restrict__ Out)
{
    __shared__ ushort a_sm[128 * 32];
    const int tid = threadIdx.x;
    const int w = tid >> 6, l = tid & 63, lq = l & 15, lg = l >> 4;
    const int wm = w >> 1, wn = w & 1;
    const int m0 = blockIdx.y * 128, n0 = blockIdx.x * 128;
    f32x4 acc[4][4];
#pragma unroll
    for (int i = 0; i < 4; ++i)
#pragma unroll
        for (int j = 0; j < 4; ++j) acc[i][j] = (f32x4){0.f, 0.f, 0.f, 0.f};

    for (int k0 = 0; k0 < 512; k0 += 32) {
        __syncthreads();
#pragma unroll
        for (int it = 0; it < 2; ++it) {
            int L = it * 256 + tid;
            int row = L >> 2, c = L & 3;
            int p = c ^ ((row >> 1) & 3);
            size_t idx = (size_t)(m0 + row) * Dm + k0 + c * 8;
            short8 v0 = *(const short8*)(P0 + idx);
            short8 v1 = *(const short8*)(P1 + idx);
            short8 v2 = *(const short8*)(P2 + idx);
            short8 v3 = *(const short8*)(P3 + idx);
            short8 sum;
#pragma unroll
            for (int j = 0; j < 8; ++j) {
                float s = (bf2f((ushort)v0[j]) + bf2f((ushort)v1[j])) +
                          (bf2f((ushort)v2[j]) + bf2f((ushort)v3[j]));
                sum[j] = (short)f2bf(s);
            }
            *(short8*)&a_sm[row * 32 + p * 8] = sum;
        }
        __syncthreads();
        short8 bfrag[4];
#pragma unroll
        for (int ns = 0; ns < 4; ++ns)
            bfrag[ns] = *(const short8*)(Wch + (size_t)(n0 + wn * 64 + ns * 16 + lq) * Dm + k0 + lg * 8);
#pragma unroll
        for (int ms = 0; ms < 4; ++ms) {
            int row = wm * 64 + ms * 16 + lq;
            int p = lg ^ ((row >> 1) & 3);
            short8 afrag = *(const short8*)&a_sm[row * 32 + p * 8];
#pragma unroll
            for (int ns = 0; ns < 4; ++ns)
                acc[ms][ns] = __builtin_amdgcn_mfma_f32_16x16x32_bf16(afrag, bfrag[ns], acc[ms][ns], 0, 0, 0);
        }
    }
#pragma unroll
    for (int ms = 0; ms < 4; ++ms)
#pragma unroll
        for (int ns = 0; ns < 4; ++ns)
#pragma unroll
            for (int j = 0; j < 4; ++j) {
                int m = m0 + wm * 64 + ms * 16 + lg * 4 + j;
                int n = n0 + wn * 64 + ns * 16 + lq;
                Out[(size_t)m * Dm + n] = fmaxf(acc[ms][ns][j], 0.0f);
            }
}

extern "C" void kernel_launch(void* const* d_in, const int* in_sizes, int n_in,
                              void* d_out, int out_size, void* d_ws, size_t ws_size,
                              hipStream_t stream)
{
    const float* x  = (const float*)d_in[0];
    const float* Wq = (const float*)d_in[1];
    const float* Wk = (const float*)d_in[2];
    const float* Wv = (const float*)d_in[3];
    const float* Wc = (const float*)d_in[4];
    float* out = (float*)d_out;

    const size_t SZ = 4194304;   // 2*4096*512
    const size_t WZ = 262144;    // 512*512
    ushort* ws16 = (ushort*)d_ws;
    ushort* Xh  = ws16;           // reused as P0 after qkv
    ushort* Xl  = Xh + SZ;        // reused as P1 after qkv
    ushort* Wqh = Xl + SZ;
    ushort* Wql = Wqh + WZ;
    ushort* Wkh = Wql + WZ;
    ushort* Wkl = Wkh + WZ;
    ushort* Wvh = Wkl + WZ;
    ushort* Wch = Wvh + WZ;
    ushort* Qh  = Wch + WZ;
    ushort* Ql  = Qh + SZ;
    ushort* Kh  = Ql + SZ;
    ushort* Kl  = Kh + SZ;
    ushort* Vb  = Kl + SZ;        // reused as P2 after vt_transpose
    ushort* Vt  = Vb + SZ;
    ushort* P3  = Vt + SZ;        // end: 9*SZ + 6*WZ = ~75.5 MB

    cast_split<<<2560, 256, 0, stream>>>(x, Wq, Wk, Wv, Wc, Xh, Xl,
                                         Wqh, Wql, Wkh, Wkl, Wvh, Wch);
    qkv_gemm<<<dim3(4, 64, 3), 256, 0, stream>>>(Xh, Xl, Wqh, Wql, Wkh, Wkl, Wvh,
                                                 Qh, Ql, Kh, Kl, Vb);
    vt_transpose<<<dim3(64, 8, 2), 256, 0, stream>>>(Vb, Vt);
    attn_fused<<<dim3(64, 2, 4), 256, 0, stream>>>(Qh, Ql, Kh, Kl, Vt,
                                                   Xh, Xl, Vb, P3);
    out_gemm<<<dim3(4, 64), 256, 0, stream>>>(Xh, Xl, Vb, P3, Wch, out);
}

// Round 4
// 844.350 us; speedup vs baseline: 3.5425x; 1.3811x over previous
//
#include <hip/hip_runtime.h>

typedef __attribute__((ext_vector_type(8))) short short8;
typedef __attribute__((ext_vector_type(4))) float f32x4;
typedef __attribute__((ext_vector_type(4))) int i32x4;

#define S 4096
#define Dm 512

__device__ __forceinline__ ushort f2bf(float f) {
    union { float f; unsigned u; } v; v.f = f;
    unsigned r = v.u + 0x7FFFu + ((v.u >> 16) & 1u);
    return (ushort)(r >> 16);
}
__device__ __forceinline__ float bf2f(ushort h) {
    union { unsigned u; float f; } v; v.u = ((unsigned)h) << 16; return v.f;
}

__device__ __forceinline__ void gload_lds16(const ushort* g, ushort* l) {
    __builtin_amdgcn_global_load_lds(
        (const __attribute__((address_space(1))) unsigned int*)g,
        (__attribute__((address_space(3))) unsigned int*)l, 16, 0, 0);
}

// ------------- kernel 1: cast fp32 -> bf16 hi/lo splits -------------
__global__ void cast_split(const float* __restrict__ x,
                           const float* __restrict__ Wq, const float* __restrict__ Wk,
                           const float* __restrict__ Wv, const float* __restrict__ Wc,
                           ushort* __restrict__ Xh, ushort* __restrict__ Xl,
                           ushort* __restrict__ Wqh, ushort* __restrict__ Wql,
                           ushort* __restrict__ Wkh, ushort* __restrict__ Wkl,
                           ushort* __restrict__ Wvh, ushort* __restrict__ Wch)
{
    const size_t i8 = ((size_t)blockIdx.x * 256 + threadIdx.x) * 8;
    const size_t NX = 4194304;
    float v[8];
    if (i8 < NX) {
        float4 a = *(const float4*)(x + i8);
        float4 b = *(const float4*)(x + i8 + 4);
        v[0]=a.x; v[1]=a.y; v[2]=a.z; v[3]=a.w; v[4]=b.x; v[5]=b.y; v[6]=b.z; v[7]=b.w;
        short8 h8, l8;
#pragma unroll
        for (int j = 0; j < 8; ++j) {
            ushort hi = f2bf(v[j]);
            h8[j] = (short)hi;
            l8[j] = (short)f2bf(v[j] - bf2f(hi));
        }
        *(short8*)(Xh + i8) = h8;
        *(short8*)(Xl + i8) = l8;
    } else {
        size_t j0 = i8 - NX;
        int wsel = (int)(j0 >> 18);
        size_t off = j0 & 262143;
        const float* src = (wsel == 0) ? Wq : (wsel == 1) ? Wk : (wsel == 2) ? Wv : Wc;
        float4 a = *(const float4*)(src + off);
        float4 b = *(const float4*)(src + off + 4);
        v[0]=a.x; v[1]=a.y; v[2]=a.z; v[3]=a.w; v[4]=b.x; v[5]=b.y; v[6]=b.z; v[7]=b.w;
        short8 h8, l8;
#pragma unroll
        for (int j = 0; j < 8; ++j) {
            ushort hi = f2bf(v[j]);
            h8[j] = (short)hi;
            l8[j] = (short)f2bf(v[j] - bf2f(hi));
        }
        ushort* dh = (wsel == 0) ? Wqh : (wsel == 1) ? Wkh : (wsel == 2) ? Wvh : Wch;
        *(short8*)(dh + off) = h8;
        if (wsel < 2) {
            ushort* dl = wsel ? Wkl : Wql;
            *(short8*)(dl + off) = l8;
        }
    }
}

// ------------- kernel 2: QKV projection (bf16 MFMA; Q,K split, 3-term) ----
__global__ __launch_bounds__(256, 2)
void qkv_gemm(const ushort* __restrict__ Xh, const ushort* __restrict__ Xl,
              const ushort* __restrict__ Wqh, const ushort* __restrict__ Wql,
              const ushort* __restrict__ Wkh, const ushort* __restrict__ Wkl,
              const ushort* __restrict__ Wvh,
              ushort* __restrict__ Qh, ushort* __restrict__ Ql,
              ushort* __restrict__ Kh, ushort* __restrict__ Kl,
              ushort* __restrict__ Vb)
{
    __shared__ ushort xh_sm[128 * 32];
    __shared__ ushort xl_sm[128 * 32];
    const int tid = threadIdx.x;
    const int w = tid >> 6, l = tid & 63, lq = l & 15, lg = l >> 4;
    const int wm = w >> 1, wn = w & 1;
    const int z = blockIdx.z;
    const int m0 = blockIdx.y * 128, n0 = blockIdx.x * 128;
    const ushort* Wh = (z == 0) ? Wqh : (z == 1) ? Wkh : Wvh;
    const ushort* Wl = (z == 0) ? Wql : Wkl;   // unused when z==2

    f32x4 acc[4][4];
#pragma unroll
    for (int i = 0; i < 4; ++i)
#pragma unroll
        for (int j = 0; j < 4; ++j) acc[i][j] = (f32x4){0.f, 0.f, 0.f, 0.f};

    for (int k0 = 0; k0 < 512; k0 += 32) {
        __syncthreads();
#pragma unroll
        for (int it = 0; it < 2; ++it) {
            int L = it * 256 + tid;
            int row = L >> 2, c = L & 3;
            int p = c ^ ((row >> 1) & 3);
            short8 vv = *(const short8*)(Xh + (size_t)(m0 + row) * Dm + k0 + c * 8);
            *(short8*)&xh_sm[row * 32 + p * 8] = vv;
            if (z < 2) {
                short8 v2 = *(const short8*)(Xl + (size_t)(m0 + row) * Dm + k0 + c * 8);
                *(short8*)&xl_sm[row * 32 + p * 8] = v2;
            }
        }
        __syncthreads();
        short8 bh[4], bl[4];
#pragma unroll
        for (int ns = 0; ns < 4; ++ns) {
            bh[ns] = *(const short8*)(Wh + (size_t)(n0 + wn * 64 + ns * 16 + lq) * Dm + k0 + lg * 8);
            if (z < 2)
                bl[ns] = *(const short8*)(Wl + (size_t)(n0 + wn * 64 + ns * 16 + lq) * Dm + k0 + lg * 8);
        }
#pragma unroll
        for (int ms = 0; ms < 4; ++ms) {
            int row = wm * 64 + ms * 16 + lq;
            int p = lg ^ ((row >> 1) & 3);
            short8 ah = *(const short8*)&xh_sm[row * 32 + p * 8];
            if (z < 2) {
                short8 al = *(const short8*)&xl_sm[row * 32 + p * 8];
#pragma unroll
                for (int ns = 0; ns < 4; ++ns) {
                    acc[ms][ns] = __builtin_amdgcn_mfma_f32_16x16x32_bf16(ah, bh[ns], acc[ms][ns], 0, 0, 0);
                    acc[ms][ns] = __builtin_amdgcn_mfma_f32_16x16x32_bf16(ah, bl[ns], acc[ms][ns], 0, 0, 0);
                    acc[ms][ns] = __builtin_amdgcn_mfma_f32_16x16x32_bf16(al, bh[ns], acc[ms][ns], 0, 0, 0);
                }
            } else {
#pragma unroll
                for (int ns = 0; ns < 4; ++ns)
                    acc[ms][ns] = __builtin_amdgcn_mfma_f32_16x16x32_bf16(ah, bh[ns], acc[ms][ns], 0, 0, 0);
            }
        }
    }
    ushort* Yh = (z == 0) ? Qh : (z == 1) ? Kh : Vb;
    ushort* Yl = (z == 0) ? Ql : Kl;
#pragma unroll
    for (int ms = 0; ms < 4; ++ms)
#pragma unroll
        for (int ns = 0; ns < 4; ++ns)
#pragma unroll
            for (int j = 0; j < 4; ++j) {
                int m = m0 + wm * 64 + ms * 16 + lg * 4 + j;
                int n = n0 + wn * 64 + ns * 16 + lq;
                float v = acc[ms][ns][j];
                ushort hi = f2bf(v);
                Yh[(size_t)m * Dm + n] = hi;
                if (z < 2) Yl[(size_t)m * Dm + n] = f2bf(v - bf2f(hi));
            }
}

// ------------- kernel 3: V -> V^T k-tiled  [b][s/16][f][16], half-swizzled ---
__global__ void vt_transpose(const ushort* __restrict__ Vb, ushort* __restrict__ VtG)
{
    __shared__ ushort t_sm[64 * 65];
    const int tid = threadIdx.x;
    const int bz = blockIdx.z;
    const int s0 = blockIdx.x * 64;
    const int f0 = blockIdx.y * 64;
#pragma unroll
    for (int it = 0; it < 2; ++it) {
        int r = it * 32 + (tid >> 3);
        int c8 = tid & 7;
        short8 v = *(const short8*)(Vb + (size_t)bz * S * Dm + (size_t)(s0 + r) * Dm + f0 + c8 * 8);
#pragma unroll
        for (int j = 0; j < 8; ++j) t_sm[(c8 * 8 + j) * 65 + r] = (ushort)v[j];
    }
    __syncthreads();
#pragma unroll
    for (int it = 0; it < 2; ++it) {
        int fr = it * 32 + (tid >> 3);
        int sc8 = tid & 7;
        short8 o;
#pragma unroll
        for (int j = 0; j < 8; ++j) o[j] = (short)t_sm[fr * 65 + sc8 * 8 + j];
        int d = f0 + fr;
        int ktile = (s0 >> 4) + (sc8 >> 1);
        int half = (sc8 & 1) ^ ((d >> 2) & 1);   // bank-spread swizzle for PV reads
        *(short8*)(VtG + (((size_t)bz * 256 + ktile) * 512 + d) * 16 + half * 8) = o;
    }
}

// ------------- kernel 4: fused attention -------------
// 64 q/block (4 waves x 16 q), k-range 1024 (ks of 4), tile KT=16, double-buffered.
// Softmax over HEADS is lane-local; PV A-frag built via ds_bpermute (zero-padded
// 16x16x32). Precision: 1-term bf16 scores + ballot-gated rare 3-term redo.
__global__ __launch_bounds__(256, 2)
void attn_fused(const ushort* __restrict__ Qhh, const ushort* __restrict__ Qll,
                const ushort* __restrict__ Khh, const ushort* __restrict__ Kll,
                const ushort* __restrict__ VtG,
                ushort* __restrict__ P0, ushort* __restrict__ P1,
                ushort* __restrict__ P2, ushort* __restrict__ P3)
{
    __shared__ __align__(16) ushort Khi[2][8192];   // [buf][16 k][64 chunk-slots]
    __shared__ __align__(16) ushort Vt[2][8192];    // [buf][512 d][16 k] (half-swz)
    const int tid = threadIdx.x;
    const int w = tid >> 6, l = tid & 63, lq = l & 15, lg = l >> 4;
    const int bid = blockIdx.x;
    const int qt = bid >> 3, grp = bid & 7;     // grp -> XCD: each XCD owns one (bb,ks)
    const int bb = grp >> 2, ks = grp & 3;
    const int q_first = qt * 64;
    const int kbeg = ks * 1024;
    const int qsc = q_first + w * 16 + lq;
    const size_t sbase = (size_t)bb * S * Dm;
    const size_t qoff = sbase + (size_t)qsc * Dm;
    const size_t vbase = (size_t)bb * 256 * 8192;
    ushort* __restrict__ Pp = (ks == 0) ? P0 : (ks == 1) ? P1 : (ks == 2) ? P2 : P3;

    // persistent Q-hi fragments (B-operand: 8 contiguous d per lane)
    short8 qf[8][2];
#pragma unroll
    for (int h = 0; h < 8; ++h)
#pragma unroll
        for (int ds = 0; ds < 2; ++ds)
            qf[h][ds] = *(const short8*)(Qhh + qoff + h * 64 + ds * 32 + lg * 8);

    f32x4 outa[8][4];
#pragma unroll
    for (int h = 0; h < 8; ++h)
#pragma unroll
        for (int d = 0; d < 4; ++d) outa[h][d] = (f32x4){0.f, 0.f, 0.f, 0.f};

#define STAGE(KC, BUF) do {                                                      \
    const int k0s = kbeg + (KC) * 16;                                            \
    _Pragma("unroll") for (int it = 0; it < 4; ++it) {                           \
        int L = it * 256 + tid; int row = L >> 6; int ch = (L & 63) ^ (row & 7); \
        gload_lds16(Khh + sbase + (size_t)(k0s + row) * Dm + ch * 8,             \
                    &Khi[BUF][L * 8]); }                                         \
    _Pragma("unroll") for (int it = 0; it < 4; ++it) {                           \
        int L = it * 256 + tid;                                                  \
        gload_lds16(VtG + vbase + (size_t)(k0s >> 4) * 8192 + L * 8,             \
                    &Vt[BUF][L * 8]); }                                          \
} while (0)

    STAGE(0, 0);
    for (int kc = 0; kc < 64; ++kc) {
        const int pb = kc & 1;
        const int k0 = kbeg + kc * 16;
        if (kc < 63) {
            STAGE(kc + 1, pb ^ 1);
            asm volatile("s_waitcnt vmcnt(8)" ::: "memory");   // prior buf's 8 done
        } else {
            asm volatile("s_waitcnt vmcnt(0)" ::: "memory");
        }
        __builtin_amdgcn_sched_barrier(0);
        __builtin_amdgcn_s_barrier();
        __builtin_amdgcn_sched_barrier(0);

        // ---- scores: 1-term bf16 (S^T: lane holds k=lg*4+j rows, q=lq col) ----
        f32x4 sc[8];
#pragma unroll
        for (int h = 0; h < 8; ++h) sc[h] = (f32x4){0.f, 0.f, 0.f, 0.f};
#pragma unroll
        for (int h = 0; h < 8; ++h)
#pragma unroll
            for (int ds = 0; ds < 2; ++ds) {
                int unit = lq * 64 + ((h * 8 + ds * 4 + lg) ^ (lq & 7));
                short8 khf = *(const short8*)&Khi[pb][unit * 8];
                sc[h] = __builtin_amdgcn_mfma_f32_16x16x32_bf16(khf, qf[h][ds], sc[h], 0, 0, 0);
            }

        // ---- masked-boundary uncertainty; rare 3-term redo (ballot-gated) ----
        const int kb = k0 + lg * 4;
        bool flag = false;
#pragma unroll
        for (int j = 0; j < 4; ++j) {
            if ((kb + j) > qsc) {
#pragma unroll
                for (int h = 0; h < 8; ++h) {
                    float a = fabsf(sc[h][j]);
                    flag = flag || (fabsf(a - 32.0f) < 0.26f);
                }
            }
        }
        if (__ballot(flag)) {
            f32x4 s2[8];
#pragma unroll
            for (int h = 0; h < 8; ++h) s2[h] = (f32x4){0.f, 0.f, 0.f, 0.f};
#pragma unroll
            for (int h = 0; h < 8; ++h)
#pragma unroll
                for (int ds = 0; ds < 2; ++ds) {
                    int unit = lq * 64 + ((h * 8 + ds * 4 + lg) ^ (lq & 7));
                    short8 khf = *(const short8*)&Khi[pb][unit * 8];
                    short8 qlf = *(const short8*)(Qll + qoff + h * 64 + ds * 32 + lg * 8);
                    short8 klf = *(const short8*)(Kll + sbase + (size_t)(k0 + lq) * Dm + h * 64 + ds * 32 + lg * 8);
                    s2[h] = __builtin_amdgcn_mfma_f32_16x16x32_bf16(khf, qf[h][ds], s2[h], 0, 0, 0);
                    s2[h] = __builtin_amdgcn_mfma_f32_16x16x32_bf16(khf, qlf, s2[h], 0, 0, 0);
                    s2[h] = __builtin_amdgcn_mfma_f32_16x16x32_bf16(klf, qf[h][ds], s2[h], 0, 0, 0);
                }
#pragma unroll
            for (int h = 0; h < 8; ++h) sc[h] = s2[h];
        }

        // ---- softmax over the 8 heads (lane-local; exact ref fp32 chain) ----
#pragma unroll
        for (int j = 0; j < 4; ++j) {
            float xx[8];
            const float madd = ((kb + j) > qsc) ? -1e9f : 0.0f;
#pragma unroll
            for (int h = 0; h < 8; ++h)
                xx[h] = (sc[h][j] + madd) * 0.125f;   // faithful fp32 rounding
            float m01 = fmaxf(xx[0], xx[1]), m23 = fmaxf(xx[2], xx[3]);
            float m45 = fmaxf(xx[4], xx[5]), m67 = fmaxf(xx[6], xx[7]);
            float mm = fmaxf(fmaxf(m01, m23), fmaxf(m45, m67));
            float e[8]; float den = 0.f;
#pragma unroll
            for (int h = 0; h < 8; ++h) { e[h] = __expf(xx[h] - mm); den += e[h]; }
            float inv = 1.0f / den;
#pragma unroll
            for (int h = 0; h < 8; ++h) sc[h][j] = e[h] * inv;
        }

        // ---- pack + bpermute into PV A-frag (zero-padded 32-k window) ----
        unsigned pk01[8], pk23[8];
#pragma unroll
        for (int h = 0; h < 8; ++h) {
            pk01[h] = (unsigned)f2bf(sc[h][0]) | ((unsigned)f2bf(sc[h][1]) << 16);
            pk23[h] = (unsigned)f2bf(sc[h][2]) | ((unsigned)f2bf(sc[h][3]) << 16);
        }
        const int a1 = (lq + 32 * (lg & 1)) * 4;
        const bool act = ((lg >> 1) == pb);
#pragma unroll
        for (int h = 0; h < 8; ++h) {
            i32x4 ai;
            ai.x = __builtin_amdgcn_ds_bpermute(a1, (int)pk01[h]);
            ai.y = __builtin_amdgcn_ds_bpermute(a1, (int)pk23[h]);
            ai.z = __builtin_amdgcn_ds_bpermute(a1 + 64, (int)pk01[h]);
            ai.w = __builtin_amdgcn_ds_bpermute(a1 + 64, (int)pk23[h]);
            if (!act) ai = (i32x4){0, 0, 0, 0};
            union { i32x4 i; short8 s; } u; u.i = ai;
#pragma unroll
            for (int dsub = 0; dsub < 4; ++dsub) {
                int drow = h * 64 + dsub * 16 + lq;
                short8 vf = *(const short8*)&Vt[pb][drow * 16 + ((((lg & 1) ^ ((drow >> 2) & 1))) << 3)];
                outa[h][dsub] = __builtin_amdgcn_mfma_f32_16x16x32_bf16(u.s, vf, outa[h][dsub], 0, 0, 0);
            }
        }
        __builtin_amdgcn_sched_barrier(0);
        __builtin_amdgcn_s_barrier();   // all waves done with buf pb before overwrite
        __builtin_amdgcn_sched_barrier(0);
    }
#undef STAGE

    // epilogue: partial P (this k-split) as bf16
#pragma unroll
    for (int h = 0; h < 8; ++h)
#pragma unroll
        for (int dsub = 0; dsub < 4; ++dsub)
#pragma unroll
            for (int j = 0; j < 4; ++j) {
                int qrow = q_first + w * 16 + lg * 4 + j;
                Pp[sbase + (size_t)qrow * Dm + h * 64 + dsub * 16 + lq] = f2bf(outa[h][dsub][j]);
            }
}

// ------------- kernel 5: out projection + ReLU (sums 4 partials, fp32 out) ----
__global__ __launch_bounds__(256, 2)
void out_gemm(const ushort* __restrict__ P0, const ushort* __restrict__ P1,
              const ushort* __restrict__ P2, const ushort* __restrict__ P3,
              const ushort* __restrict__ Wch, float* __restrict__ Out)
{
    __shared__ ushort a_sm[128 * 32];
    const int tid = threadIdx.x;
    const int w = tid >> 6, l = tid & 63, lq = l & 15, lg = l >> 4;
    const int wm = w >> 1, wn = w & 1;
    const int m0 = blockIdx.y * 128, n0 = blockIdx.x * 128;
    f32x4 acc[4][4];
#pragma unroll
    for (int i = 0; i < 4; ++i)
#pragma unroll
        for (int j = 0; j < 4; ++j) acc[i][j] = (f32x4){0.f, 0.f, 0.f, 0.f};

    for (int k0 = 0; k0 < 512; k0 += 32) {
        __syncthreads();
#pragma unroll
        for (int it = 0; it < 2; ++it) {
            int L = it * 256 + tid;
            int row = L >> 2, c = L & 3;
            int p = c ^ ((row >> 1) & 3);
            size_t idx = (size_t)(m0 + row) * Dm + k0 + c * 8;
            short8 v0 = *(const short8*)(P0 + idx);
            short8 v1 = *(const short8*)(P1 + idx);
            short8 v2 = *(const short8*)(P2 + idx);
            short8 v3 = *(const short8*)(P3 + idx);
            short8 sum;
#pragma unroll
            for (int j = 0; j < 8; ++j) {
                float s = (bf2f((ushort)v0[j]) + bf2f((ushort)v1[j])) +
                          (bf2f((ushort)v2[j]) + bf2f((ushort)v3[j]));
                sum[j] = (short)f2bf(s);
            }
            *(short8*)&a_sm[row * 32 + p * 8] = sum;
        }
        __syncthreads();
        short8 bfrag[4];
#pragma unroll
        for (int ns = 0; ns < 4; ++ns)
            bfrag[ns] = *(const short8*)(Wch + (size_t)(n0 + wn * 64 + ns * 16 + lq) * Dm + k0 + lg * 8);
#pragma unroll
        for (int ms = 0; ms < 4; ++ms) {
            int row = wm * 64 + ms * 16 + lq;
            int p = lg ^ ((row >> 1) & 3);
            short8 afrag = *(const short8*)&a_sm[row * 32 + p * 8];
#pragma unroll
            for (int ns = 0; ns < 4; ++ns)
                acc[ms][ns] = __builtin_amdgcn_mfma_f32_16x16x32_bf16(afrag, bfrag[ns], acc[ms][ns], 0, 0, 0);
        }
    }
#pragma unroll
    for (int ms = 0; ms < 4; ++ms)
#pragma unroll
        for (int ns = 0; ns < 4; ++ns)
#pragma unroll
            for (int j = 0; j < 4; ++j) {
                int m = m0 + wm * 64 + ms * 16 + lg * 4 + j;
                int n = n0 + wn * 64 + ns * 16 + lq;
                Out[(size_t)m * Dm + n] = fmaxf(acc[ms][ns][j], 0.0f);
            }
}

extern "C" void kernel_launch(void* const* d_in, const int* in_sizes, int n_in,
                              void* d_out, int out_size, void* d_ws, size_t ws_size,
                              hipStream_t stream)
{
    const float* x  = (const float*)d_in[0];
    const float* Wq = (const float*)d_in[1];
    const float* Wk = (const float*)d_in[2];
    const float* Wv = (const float*)d_in[3];
    const float* Wc = (const float*)d_in[4];
    float* out = (float*)d_out;

    const size_t SZ = 4194304;   // 2*4096*512
    const size_t WZ = 262144;    // 512*512
    ushort* ws16 = (ushort*)d_ws;
    ushort* Xh  = ws16;           // reused as P0 after qkv
    ushort* Xl  = Xh + SZ;        // reused as P1 after qkv
    ushort* Wqh = Xl + SZ;
    ushort* Wql = Wqh + WZ;
    ushort* Wkh = Wql + WZ;
    ushort* Wkl = Wkh + WZ;
    ushort* Wvh = Wkl + WZ;
    ushort* Wch = Wvh + WZ;
    ushort* Qh  = Wch + WZ;
    ushort* Ql  = Qh + SZ;
    ushort* Kh  = Ql + SZ;
    ushort* Kl  = Kh + SZ;
    ushort* Vb  = Kl + SZ;        // reused as P2 after vt_transpose
    ushort* Vt  = Vb + SZ;
    ushort* P3  = Vt + SZ;        // total ~75.5 MB

    cast_split<<<2560, 256, 0, stream>>>(x, Wq, Wk, Wv, Wc, Xh, Xl,
                                         Wqh, Wql, Wkh, Wkl, Wvh, Wch);
    qkv_gemm<<<dim3(4, 64, 3), 256, 0, stream>>>(Xh, Xl, Wqh, Wql, Wkh, Wkl, Wvh,
                                                 Qh, Ql, Kh, Kl, Vb);
    vt_transpose<<<dim3(64, 8, 2), 256, 0, stream>>>(Vb, Vt);
    attn_fused<<<dim3(512), 256, 0, stream>>>(Qh, Ql, Kh, Kl, Vt,
                                              Xh, Xl, Vb, P3);
    out_gemm<<<dim3(4, 64), 256, 0, stream>>>(Xh, Xl, Vb, P3, Wch, out);
}